// Round 18
// baseline (92.207 us; speedup 1.0000x reference)
//
#include <hip/hip_runtime.h>
#include <hip/hip_bf16.h>

#define B_ 8
#define SPREV 4095
#define S_ 4096
#define E_ 2048
#define H_ 16
#define HD_ 128
#define LOW_ 512
#define NCH 128     // attention s-chunks per batch
#define CHK 32      // positions per chunk
#define L2INV 0.207620506f   // log2(10000)/64

typedef short s8v __attribute__((ext_vector_type(8)));
typedef float f4v __attribute__((ext_vector_type(4)));

#define GAS(p) ((const __attribute__((address_space(1))) void*)(p))
#define LAS(p) ((__attribute__((address_space(3))) void*)(p))

__device__ __forceinline__ short f2bf_s(float f) {
  return (short)__bfloat16_as_ushort(__float2bfloat16(f));
}
__device__ __forceinline__ float bf2f(unsigned short h) {
  union { unsigned u; float f; } v; v.u = ((unsigned)h) << 16;
  return v.f;
}

// Zero all accumulation targets (55296 ws floats + 16384 out floats).
__global__ __launch_bounds__(256) void init_kernel(float* __restrict__ ws_pre,
                                                   float* __restrict__ out) {
  int i = blockIdx.x * 256 + threadIdx.x;
  if (i < 55296) ws_pre[i] = 0.f;           // Cq,Qc,qr_pre,ckvn,krn,o_heads
  else if (i < 71680) out[i - 55296] = 0.f;
}

// out[b][n] += sum_k x[b][k] * W[k][n], k in [k0, k0+32).
__global__ __launch_bounds__(128) void matvec8(
    const float* __restrict__ x, int K,
    const float* __restrict__ W0, int N0, float* __restrict__ o0,
    const float* __restrict__ W1, int N1, float* __restrict__ o1,
    const float* __restrict__ W2, int N2, float* __restrict__ o2)
{
  int cb = blockIdx.x;
  int nb0 = N0 >> 7, nb1 = N1 >> 7;
  const float* W; float* o; int N, colbase;
  if (cb < nb0)            { W = W0; o = o0; N = N0; colbase = cb << 7; }
  else if (cb < nb0 + nb1) { W = W1; o = o1; N = N1; colbase = (cb - nb0) << 7; }
  else                     { W = W2; o = o2; N = N2; colbase = (cb - nb0 - nb1) << 7; }
  int col = colbase + threadIdx.x;
  int k0 = blockIdx.y * 32;
  float acc[B_];
  #pragma unroll
  for (int b = 0; b < B_; ++b) acc[b] = 0.f;
  const float* Wp = W + (size_t)k0 * N + col;
  #pragma unroll 8
  for (int k = 0; k < 32; ++k) {
    float wv = Wp[(size_t)k * N];
    #pragma unroll
    for (int b = 0; b < B_; ++b)
      acc[b] = fmaf(x[b * K + k0 + k], wv, acc[b]);   // uniform -> s_load
  }
  #pragma unroll
  for (int b = 0; b < B_; ++b) atomicAdd(&o[b * N + col], acc[b]);
}

// qeff[b,h,l] = sum_d FU[l, h*128+d] * Qc[b, h*128+d]; grid (64, 8) x 256.
__global__ __launch_bounds__(256) void qeff_kernel(
    const float* __restrict__ Qc, const float* __restrict__ FU,
    unsigned short* __restrict__ qeff)
{
  int bx = blockIdx.x, b = blockIdx.y, t = threadIdx.x;
  int h = bx >> 2, lq = bx & 3;
  int g = t >> 4, li = t & 15;
  __shared__ float qs[HD_];
  if (t < 128) qs[t] = Qc[b * E_ + h * HD_ + t];
  __syncthreads();
  f4v q0 = *(const f4v*)&qs[li * 8];
  f4v q1 = *(const f4v*)&qs[li * 8 + 4];
  #pragma unroll 2
  for (int p = 0; p < 8; ++p) {
    int l = lq * 128 + p * 16 + g;
    const f4v* w4 = (const f4v*)(FU + (size_t)l * (2 * E_) + h * HD_ + li * 8);
    f4v w0 = w4[0], w1 = w4[1];
    float a = w0[0]*q0[0] + w0[1]*q0[1] + w0[2]*q0[2] + w0[3]*q0[3]
            + w1[0]*q1[0] + w1[1]*q1[1] + w1[2]*q1[2] + w1[3]*q1[3];
    a += __shfl_xor(a, 1); a += __shfl_xor(a, 2);
    a += __shfl_xor(a, 4); a += __shfl_xor(a, 8);
    if (li == 0) qeff[(size_t)(b * H_ + h) * LOW_ + l] = (unsigned short)f2bf_s(a);
  }
}

// Flash-decode, one (b, 32-chunk) per block, 8 waves (512 thr).
// STAGE: 32x512 f32 ckv tile -> LDS via global_load_lds width-16, coalesced
// 1KB/instr, source pre-swizzled by granule c(r)=(r&7)^((r>>3)&7).
// Phase A (8 waves): wave = (s-group w&1, k-quarter w>>1); frags from LDS.
// kq==0 waves also compute rope inline. Phase B (512 thr): softmax.
// Phase C: PV, single K=32 MFMA per nt; V column reads from LDS.
__global__ __launch_bounds__(512) void attn_kernel(
    const float* __restrict__ ckv_cache, const float* __restrict__ ckv_new,
    const unsigned short* __restrict__ qeff,
    const float* __restrict__ kr_cache, const float* __restrict__ kr_new,
    const float* __restrict__ qr_pre,
    unsigned short* __restrict__ acc_part, float* __restrict__ m_part,
    float* __restrict__ l_part)
{
  int chunk = blockIdx.x, b = blockIdx.y;
  int tid = threadIdx.x;
  int w = tid >> 6, lane = tid & 63;
  int kg = lane >> 4, l16 = lane & 15;
  __shared__ float V32[CHK * 512];          // 64 KB, granule-swizzled f32
  __shared__ float S_lds[4][16 * 32];       // [k-quarter][h*32 + (s ^ ((h&7)<<2))]
  __shared__ unsigned short P_lds[16 * 32]; // granule-swz: s ^ ((h&3)<<3)
  __shared__ float qr_sh[128];
  __shared__ float rope_lds[CHK];

  // qr rotated at position 4095 (once per block)
  if (tid < 64) {
    float invf = exp2f(-L2INV * (float)tid);
    float x1 = qr_pre[b * HD_ + tid], x2 = qr_pre[b * HD_ + 64 + tid];
    float sn, cs; sincosf(4095.0f * invf, &sn, &cs);
    qr_sh[tid]      = x1 * cs - x2 * sn;
    qr_sh[64 + tid] = x1 * sn + x2 * cs;
  }

  { // ---- STAGE: 64 segs x 1KB; wave w issues segs w*8..w*8+7 ----
    char* vbase = (char*)V32;
    #pragma unroll
    for (int i = 0; i < 8; ++i) {
      int seg = w * 8 + i;
      int r = seg >> 1, half = seg & 1;
      int sg = chunk * CHK + r;
      const float* crow = (sg == S_ - 1) ? (ckv_new + b * LOW_)
                                         : (ckv_cache + ((size_t)b * SPREV + sg) * LOW_);
      int c = (r & 7) ^ ((r >> 3) & 7);
      const float* gp = crow + (((half * 64 + lane) ^ c) << 2);
      __builtin_amdgcn_global_load_lds(GAS(gp), LAS(vbase + seg * 1024), 16, 0, 0);
    }
  }
  __syncthreads();   // compiler drains vmcnt before barrier

  { // ---- phase A: wave w = (s-group w&1, k-quarter w>>1), frags from LDS ----
    int kq = w >> 1;
    int s_loc = (w & 1) * 16 + l16;
    int c = (s_loc & 7) ^ ((s_loc >> 3) & 7);
    const float* vrow = V32 + s_loc * 512;
    f4v acc0 = {0.f, 0.f, 0.f, 0.f};
    f4v acc1 = {0.f, 0.f, 0.f, 0.f};
    const s8v* qf = (const s8v*)(qeff + (size_t)(b * H_ + l16) * LOW_);
    #pragma unroll
    for (int u = 0; u < 4; ++u) {
      int kk = kq * 4 + u;
      s8v a = qf[kk * 4 + kg];
      int g = kk * 8 + kg * 2;
      f4v c0 = *(const f4v*)(vrow + ((g ^ c) << 2));
      f4v c1 = *(const f4v*)(vrow + (((g + 1) ^ c) << 2));
      s8v bv;
      bv[0]=f2bf_s(c0[0]); bv[1]=f2bf_s(c0[1]); bv[2]=f2bf_s(c0[2]); bv[3]=f2bf_s(c0[3]);
      bv[4]=f2bf_s(c1[0]); bv[5]=f2bf_s(c1[1]); bv[6]=f2bf_s(c1[2]); bv[7]=f2bf_s(c1[3]);
      if (u & 1)
        acc1 = __builtin_amdgcn_mfma_f32_16x16x32_bf16(a, bv, acc1, 0, 0, 0);
      else
        acc0 = __builtin_amdgcn_mfma_f32_16x16x32_bf16(a, bv, acc0, 0, 0, 0);
    }
    #pragma unroll
    for (int r = 0; r < 4; ++r) {
      int h = kg * 4 + r;
      S_lds[kq][h * 32 + (s_loc ^ ((h & 7) << 2))] = acc0[r] + acc1[r];
    }
    if (kq == 0) { // rope for this s: j in [kg*16, kg*16+16), shfl reduce
      int s = chunk * CHK + s_loc;
      const float* krp = (s == S_ - 1) ? (kr_new + b * HD_)
                                       : (kr_cache + ((size_t)b * SPREV + s) * HD_);
      float fs = (float)s;
      float rdot = 0.f;
      #pragma unroll
      for (int q = 0; q < 4; ++q) {
        int j = kg * 16 + q * 4;
        f4v x1 = *(const f4v*)&krp[j];
        f4v x2 = *(const f4v*)&krp[64 + j];
        f4v qa = *(const f4v*)&qr_sh[j];
        f4v qb = *(const f4v*)&qr_sh[64 + j];
        #pragma unroll
        for (int k2 = 0; k2 < 4; ++k2) {
          float invf = exp2f(-L2INV * (float)(j + k2));
          float sn, cs; sincosf(fs * invf, &sn, &cs);
          rdot += qa[k2] * (x1[k2] * cs - x2[k2] * sn)
                + qb[k2] * (x1[k2] * sn + x2[k2] * cs);
        }
      }
      rdot += __shfl_xor(rdot, 16);
      rdot += __shfl_xor(rdot, 32);
      if (kg == 0) rope_lds[s_loc] = rdot;
    }
  }
  __syncthreads();

  { // ---- phase B: 512 thr; thread = (h = tid>>5, sl = tid&31) ----
    int h = tid >> 5, sl = tid & 31;
    int c2 = (h & 7) << 2;
    float v = (S_lds[0][h * 32 + (sl ^ c2)] + S_lds[1][h * 32 + (sl ^ c2)]
             + S_lds[2][h * 32 + (sl ^ c2)] + S_lds[3][h * 32 + (sl ^ c2)]
             + rope_lds[sl]) * 0.0625f;
    float m = v;
    m = fmaxf(m, __shfl_xor(m, 1));  m = fmaxf(m, __shfl_xor(m, 2));
    m = fmaxf(m, __shfl_xor(m, 4));  m = fmaxf(m, __shfl_xor(m, 8));
    m = fmaxf(m, __shfl_xor(m, 16));
    float e = expf(v - m);
    float lsum = e;
    lsum += __shfl_xor(lsum, 1);  lsum += __shfl_xor(lsum, 2);
    lsum += __shfl_xor(lsum, 4);  lsum += __shfl_xor(lsum, 8);
    lsum += __shfl_xor(lsum, 16);
    P_lds[h * 32 + (sl ^ ((h & 3) << 3))] = (unsigned short)f2bf_s(e);
    if (sl == 0) {
      int idx = (b * NCH + chunk) * H_ + h;
      m_part[idx] = m;
      l_part[idx] = lsum;
    }
  }
  __syncthreads();

  { // ---- phase C: wave w owns l in [w*64, w*64+64); V cols from LDS ----
    s8v pa = *(const s8v*)&P_lds[l16 * 32 + ((kg * 8) ^ ((l16 & 3) << 3))];
    f4v oa[4];
    #pragma unroll
    for (int nt = 0; nt < 4; ++nt) oa[nt] = {0.f, 0.f, 0.f, 0.f};
    #pragma unroll
    for (int nt = 0; nt < 4; ++nt) {
      int l = w * 64 + nt * 16 + l16;
      int g = l >> 2, e = l & 3;
      s8v bv;
      #pragma unroll
      for (int i = 0; i < 8; ++i) {
        int r = kg * 8 + i;
        int c = (r & 7) ^ ((r >> 3) & 7);
        bv[i] = f2bf_s(V32[r * 512 + ((g ^ c) << 2) + e]);
      }
      oa[nt] = __builtin_amdgcn_mfma_f32_16x16x32_bf16(pa, bv, oa[nt], 0, 0, 0);
    }
    size_t base = (size_t)(b * NCH + chunk) * H_;
    #pragma unroll
    for (int nt = 0; nt < 4; ++nt) {
      int l = w * 64 + nt * 16 + l16;
      #pragma unroll
      for (int r = 0; r < 4; ++r) {
        int h = kg * 4 + r;
        acc_part[(base + h) * LOW_ + l] = (unsigned short)f2bf_s(oa[nt][r]);
      }
    }
  }
}

// Fused combine + project; 128 chunks now (cross-wave reduce).
// grid (16,8,8) x 128 thr.
__global__ __launch_bounds__(128) void reduce_proj_kernel(
    const float* __restrict__ m_part, const float* __restrict__ l_part,
    const unsigned short* __restrict__ acc_part, const float* __restrict__ FU,
    float* __restrict__ o_heads)
{
  int h = blockIdx.x, b = blockIdx.y, lz = blockIdx.z, t = threadIdx.x;
  int w = t >> 6, lane = t & 63;
  __shared__ float wls[NCH];
  __shared__ float red[4];
  __shared__ float pa0[128], pa1[128];
  __shared__ float wl_sh[64];
  float mc = m_part[(b * NCH + t) * H_ + h];
  float M = mc;
  #pragma unroll
  for (int d = 1; d < 64; d <<= 1) M = fmaxf(M, __shfl_xor(M, d));
  if (lane == 0) red[w] = M;
  __syncthreads();
  M = fmaxf(red[0], red[1]);
  float wc = expf(mc - M);
  wls[t] = wc;
  float L = l_part[(b * NCH + t) * H_ + h] * wc;
  #pragma unroll
  for (int d = 1; d < 64; d <<= 1) L += __shfl_xor(L, d);
  if (lane == 0) red[2 + w] = L;
  __syncthreads();
  float Linv = 1.0f / (red[2] + red[3]);
  {
    int p = t & 31, ch = t >> 5;
    int l0 = lz * 64 + p * 2;
    float a0 = 0.f, a1 = 0.f;
    const unsigned short* ap =
        acc_part + ((size_t)(b * NCH + ch * 32) * H_ + h) * LOW_ + l0;
    #pragma unroll 4
    for (int c = 0; c < 32; ++c) {
      unsigned pk = *(const unsigned*)(ap + (size_t)c * H_ * LOW_);
      float wc2 = wls[ch * 32 + c];
      a0 = fmaf(bf2f((unsigned short)(pk & 0xffffu)), wc2, a0);
      a1 = fmaf(bf2f((unsigned short)(pk >> 16)),     wc2, a1);
    }
    pa0[t] = a0; pa1[t] = a1;
  }
  __syncthreads();
  if (t < 32) {
    float s0 = pa0[t] + pa0[t + 32] + pa0[t + 64] + pa0[t + 96];
    float s1 = pa1[t] + pa1[t + 32] + pa1[t + 64] + pa1[t + 96];
    wl_sh[t * 2]     = s0 * Linv;
    wl_sh[t * 2 + 1] = s1 * Linv;
  }
  __syncthreads();
  {
    float a = 0.f;
    const float* fp = FU + (size_t)(lz * 64) * (2 * E_) + E_ + h * HD_ + t;
    #pragma unroll 4
    for (int l = 0; l < 64; ++l)
      a = fmaf(wl_sh[l], fp[(size_t)l * (2 * E_)], a);
    atomicAdd(&o_heads[(b * H_ + h) * HD_ + t], a);
  }
}

extern "C" void kernel_launch(void* const* d_in, const int* in_sizes, int n_in,
                              void* d_out, int out_size, void* d_ws, size_t ws_size,
                              hipStream_t stream)
{
  const float* x    = (const float*)d_in[0];
  const float* ckvc = (const float*)d_in[1];
  const float* krc  = (const float*)d_in[2];
  const float* Wdq  = (const float*)d_in[3];
  const float* Wuq  = (const float*)d_in[4];
  const float* Wqr  = (const float*)d_in[5];
  const float* Wdkv = (const float*)d_in[6];
  const float* Wkr  = (const float*)d_in[7];
  const float* FU   = (const float*)d_in[8];
  const float* Wo   = (const float*)d_in[9];
  float* out = (float*)d_out;

  char* ws = (char*)d_ws;
  // zeroed prefix (55296 floats):
  float* Cq             = (float*)(ws + 0);        // 65536 B
  float* Qc             = (float*)(ws + 65536);    // 65536 B
  float* qr_pre         = (float*)(ws + 131072);   // 4096 B
  float* ckvn           = (float*)(ws + 135168);   // 16384 B
  float* krn            = (float*)(ws + 151552);   // 4096 B
  float* o_heads        = (float*)(ws + 155648);   // 65536 B  [prefix end 221184]
  unsigned short* qeff  = (unsigned short*)(ws + 221184);  // 131072 B
  float* m_part         = (float*)(ws + 352256);   // 65536 B
  float* l_part         = (float*)(ws + 417792);   // 65536 B
  unsigned short* accp  = (unsigned short*)(ws + 483328);  // 16777216 B (~17.3 MB)

  // Zero all atomic targets
  init_kernel<<<280, 256, 0, stream>>>((float*)ws, out);

  // Cq = x@Wdq ; ckv_new = x@Wdkv ; kr_new = x@Wkr
  matvec8<<<dim3(21, 64), 128, 0, stream>>>(x, E_, Wdq, E_, Cq,
                                            Wdkv, LOW_, ckvn, Wkr, HD_, krn);
  // Qc = Cq@Wuq ; qr_pre = Cq@Wqr
  matvec8<<<dim3(17, 64), 128, 0, stream>>>(Cq, E_, Wuq, E_, Qc,
                                            Wqr, HD_, qr_pre,
                                            (const float*)nullptr, 0, (float*)nullptr);
  qeff_kernel<<<dim3(64, 8), 256, 0, stream>>>(Qc, FU, qeff);
  attn_kernel<<<dim3(128, 8), 512, 0, stream>>>(ckvc, ckvn, qeff, krc, krn,
                                                qr_pre, accp, m_part, l_part);
  reduce_proj_kernel<<<dim3(16, 8, 8), 128, 0, stream>>>(m_part, l_part, accp,
                                                         FU, o_heads);
  // out = o_heads @ Wo
  matvec8<<<dim3(16, 64), 128, 0, stream>>>(o_heads, E_, Wo, E_, out,
                                            (const float*)nullptr, 0, (float*)nullptr,
                                            (const float*)nullptr, 0, (float*)nullptr);
}

// Round 19
// 90.556 us; speedup vs baseline: 1.0182x; 1.0182x over previous
//
#include <hip/hip_runtime.h>
#include <hip/hip_bf16.h>

#define B_ 8
#define SPREV 4095
#define S_ 4096
#define E_ 2048
#define H_ 16
#define HD_ 128
#define LOW_ 512
#define NCH 128     // attention s-chunks per batch
#define CHK 32      // positions per chunk
#define L2INV 0.207620506f   // log2(10000)/64

typedef short s8v __attribute__((ext_vector_type(8)));
typedef float f4v __attribute__((ext_vector_type(4)));

__device__ __forceinline__ short f2bf_s(float f) {
  return (short)__bfloat16_as_ushort(__float2bfloat16(f));
}
__device__ __forceinline__ float bf2f(unsigned short h) {
  union { unsigned u; float f; } v; v.u = ((unsigned)h) << 16;
  return v.f;
}

// Zero all accumulation targets (55296 ws floats + 16384 out floats).
__global__ __launch_bounds__(256) void init_kernel(float* __restrict__ ws_pre,
                                                   float* __restrict__ out) {
  int i = blockIdx.x * 256 + threadIdx.x;
  if (i < 55296) ws_pre[i] = 0.f;           // Cq,Qc,qr_pre,ckvn,krn,o_heads
  else if (i < 71680) out[i - 55296] = 0.f;
}

// out[b][n] += sum_k x[b][k] * W[k][n], k in [k0, k0+32).
__global__ __launch_bounds__(128) void matvec8(
    const float* __restrict__ x, int K,
    const float* __restrict__ W0, int N0, float* __restrict__ o0,
    const float* __restrict__ W1, int N1, float* __restrict__ o1,
    const float* __restrict__ W2, int N2, float* __restrict__ o2)
{
  int cb = blockIdx.x;
  int nb0 = N0 >> 7, nb1 = N1 >> 7;
  const float* W; float* o; int N, colbase;
  if (cb < nb0)            { W = W0; o = o0; N = N0; colbase = cb << 7; }
  else if (cb < nb0 + nb1) { W = W1; o = o1; N = N1; colbase = (cb - nb0) << 7; }
  else                     { W = W2; o = o2; N = N2; colbase = (cb - nb0 - nb1) << 7; }
  int col = colbase + threadIdx.x;
  int k0 = blockIdx.y * 32;
  float acc[B_];
  #pragma unroll
  for (int b = 0; b < B_; ++b) acc[b] = 0.f;
  const float* Wp = W + (size_t)k0 * N + col;
  #pragma unroll 8
  for (int k = 0; k < 32; ++k) {
    float wv = Wp[(size_t)k * N];
    #pragma unroll
    for (int b = 0; b < B_; ++b)
      acc[b] = fmaf(x[b * K + k0 + k], wv, acc[b]);   // uniform -> s_load
  }
  #pragma unroll
  for (int b = 0; b < B_; ++b) atomicAdd(&o[b * N + col], acc[b]);
}

// qeff[b,h,l] = sum_d FU[l, h*128+d] * Qc[b, h*128+d]; grid (64, 8) x 256.
__global__ __launch_bounds__(256) void qeff_kernel(
    const float* __restrict__ Qc, const float* __restrict__ FU,
    unsigned short* __restrict__ qeff)
{
  int bx = blockIdx.x, b = blockIdx.y, t = threadIdx.x;
  int h = bx >> 2, lq = bx & 3;
  int g = t >> 4, li = t & 15;
  __shared__ float qs[HD_];
  if (t < 128) qs[t] = Qc[b * E_ + h * HD_ + t];
  __syncthreads();
  f4v q0 = *(const f4v*)&qs[li * 8];
  f4v q1 = *(const f4v*)&qs[li * 8 + 4];
  #pragma unroll 2
  for (int p = 0; p < 8; ++p) {
    int l = lq * 128 + p * 16 + g;
    const f4v* w4 = (const f4v*)(FU + (size_t)l * (2 * E_) + h * HD_ + li * 8);
    f4v w0 = w4[0], w1 = w4[1];
    float a = w0[0]*q0[0] + w0[1]*q0[1] + w0[2]*q0[2] + w0[3]*q0[3]
            + w1[0]*q1[0] + w1[1]*q1[1] + w1[2]*q1[2] + w1[3]*q1[3];
    a += __shfl_xor(a, 1); a += __shfl_xor(a, 2);
    a += __shfl_xor(a, 4); a += __shfl_xor(a, 8);
    if (li == 0) qeff[(size_t)(b * H_ + h) * LOW_ + l] = (unsigned short)f2bf_s(a);
  }
}

// Flash-decode, one (b, 32-chunk) per block, 8 waves (512 thr).
// STAGE (reg->bf16->LDS): coalesced f32 reads, cvt, ds_write_b128 into
// granule-swizzled bf16 tile V16[32][512]; gc(r)=(r&7)^(((r>>3)&1)<<2)
// gives <=2-way conflicts in ALL phases (xor-by-4 separates kg even/odd).
// Phase A: wave=(s-group w&1, k-quarter w>>1), B-frags are direct b128
// granule reads (no cvt). Phase B: 512-thr softmax. Phase C: PV, V columns
// as scalar u16 LDS reads.
__global__ __launch_bounds__(512) void attn_kernel(
    const float* __restrict__ ckv_cache, const float* __restrict__ ckv_new,
    const unsigned short* __restrict__ qeff,
    const float* __restrict__ kr_cache, const float* __restrict__ kr_new,
    const float* __restrict__ qr_pre,
    unsigned short* __restrict__ acc_part, float* __restrict__ m_part,
    float* __restrict__ l_part)
{
  int chunk = blockIdx.x, b = blockIdx.y;
  int tid = threadIdx.x;
  int w = tid >> 6, lane = tid & 63;
  int kg = lane >> 4, l16 = lane & 15;
  __shared__ short V16[CHK * 512];          // 32 KB bf16, granule-swizzled
  __shared__ float S_lds[4][16 * 32];       // [k-quarter][h*32 + (s ^ ((h&7)<<2))]
  __shared__ unsigned short P_lds[16 * 32]; // swz: s-granule ^ ((h&3)<<3)
  __shared__ float qr_sh[128];
  __shared__ float rope_lds[CHK];

  // qr rotated at position 4095 (once per block)
  if (tid < 64) {
    float invf = exp2f(-L2INV * (float)tid);
    float x1 = qr_pre[b * HD_ + tid], x2 = qr_pre[b * HD_ + 64 + tid];
    float sn, cs; sincosf(4095.0f * invf, &sn, &cs);
    qr_sh[tid]      = x1 * cs - x2 * sn;
    qr_sh[64 + tid] = x1 * sn + x2 * cs;
  }

  { // ---- STAGE: wave w stages rows w*4..w*4+3; 16 lanes per row ----
    int r = w * 4 + (lane >> 4);
    int li = lane & 15;
    int sg = chunk * CHK + r;
    const float* crow = (sg == S_ - 1) ? (ckv_new + b * LOW_)
                                       : (ckv_cache + ((size_t)b * SPREV + sg) * LOW_);
    unsigned gc = (unsigned)((r & 7) ^ (((r >> 3) & 1) << 2));
    char* vrow = (char*)V16 + r * 1024;
    #pragma unroll
    for (int q = 0; q < 4; ++q) {
      int col = q * 128 + li * 8;            // 8 f32 per lane, coalesced
      f4v a0 = *(const f4v*)(crow + col);
      f4v a1 = *(const f4v*)(crow + col + 4);
      s8v bv;
      bv[0]=f2bf_s(a0[0]); bv[1]=f2bf_s(a0[1]); bv[2]=f2bf_s(a0[2]); bv[3]=f2bf_s(a0[3]);
      bv[4]=f2bf_s(a1[0]); bv[5]=f2bf_s(a1[1]); bv[6]=f2bf_s(a1[2]); bv[7]=f2bf_s(a1[3]);
      unsigned g = (unsigned)(q * 16 + li);  // 16B granule index = col>>3
      *(s8v*)(vrow + ((g ^ gc) << 4)) = bv;
    }
  }
  __syncthreads();

  { // ---- phase A: wave w = (s-group w&1, k-quarter w>>1); B-frags from LDS ----
    int kq = w >> 1;
    int s_loc = (w & 1) * 16 + l16;
    unsigned gc = (unsigned)((s_loc & 7) ^ (((s_loc >> 3) & 1) << 2));
    const char* vrow = (const char*)V16 + s_loc * 1024;
    f4v acc0 = {0.f, 0.f, 0.f, 0.f};
    f4v acc1 = {0.f, 0.f, 0.f, 0.f};
    const s8v* qf = (const s8v*)(qeff + (size_t)(b * H_ + l16) * LOW_);
    #pragma unroll
    for (int u = 0; u < 4; ++u) {
      int kk = kq * 4 + u;
      s8v a = qf[kk * 4 + kg];
      unsigned g = (unsigned)(kk * 4 + kg);  // granule of 8 bf16
      s8v bv = *(const s8v*)(vrow + ((g ^ gc) << 4));
      if (u & 1)
        acc1 = __builtin_amdgcn_mfma_f32_16x16x32_bf16(a, bv, acc1, 0, 0, 0);
      else
        acc0 = __builtin_amdgcn_mfma_f32_16x16x32_bf16(a, bv, acc0, 0, 0, 0);
    }
    #pragma unroll
    for (int r = 0; r < 4; ++r) {
      int h = kg * 4 + r;
      S_lds[kq][h * 32 + (s_loc ^ ((h & 7) << 2))] = acc0[r] + acc1[r];
    }
    if (w < 2) { // rope for this s: j in [kg*16, kg*16+16), shfl reduce
      int s = chunk * CHK + s_loc;
      const float* krp = (s == S_ - 1) ? (kr_new + b * HD_)
                                       : (kr_cache + ((size_t)b * SPREV + s) * HD_);
      float fs = (float)s;
      float rdot = 0.f;
      #pragma unroll
      for (int q = 0; q < 4; ++q) {
        int j = kg * 16 + q * 4;
        f4v x1 = *(const f4v*)&krp[j];
        f4v x2 = *(const f4v*)&krp[64 + j];
        f4v qa = *(const f4v*)&qr_sh[j];
        f4v qb = *(const f4v*)&qr_sh[64 + j];
        #pragma unroll
        for (int k2 = 0; k2 < 4; ++k2) {
          float invf = exp2f(-L2INV * (float)(j + k2));
          float sn, cs; sincosf(fs * invf, &sn, &cs);
          rdot += qa[k2] * (x1[k2] * cs - x2[k2] * sn)
                + qb[k2] * (x1[k2] * sn + x2[k2] * cs);
        }
      }
      rdot += __shfl_xor(rdot, 16);
      rdot += __shfl_xor(rdot, 32);
      if (kg == 0) rope_lds[s_loc] = rdot;
    }
  }
  __syncthreads();

  { // ---- phase B: 512 thr; thread = (h = tid>>5, sl = tid&31) ----
    int h = tid >> 5, sl = tid & 31;
    int c2 = (h & 7) << 2;
    float v = (S_lds[0][h * 32 + (sl ^ c2)] + S_lds[1][h * 32 + (sl ^ c2)]
             + S_lds[2][h * 32 + (sl ^ c2)] + S_lds[3][h * 32 + (sl ^ c2)]
             + rope_lds[sl]) * 0.0625f;
    float m = v;
    m = fmaxf(m, __shfl_xor(m, 1));  m = fmaxf(m, __shfl_xor(m, 2));
    m = fmaxf(m, __shfl_xor(m, 4));  m = fmaxf(m, __shfl_xor(m, 8));
    m = fmaxf(m, __shfl_xor(m, 16));
    float e = expf(v - m);
    float lsum = e;
    lsum += __shfl_xor(lsum, 1);  lsum += __shfl_xor(lsum, 2);
    lsum += __shfl_xor(lsum, 4);  lsum += __shfl_xor(lsum, 8);
    lsum += __shfl_xor(lsum, 16);
    P_lds[h * 32 + (sl ^ ((h & 3) << 3))] = (unsigned short)f2bf_s(e);
    if (sl == 0) {
      int idx = (b * NCH + chunk) * H_ + h;
      m_part[idx] = m;
      l_part[idx] = lsum;
    }
  }
  __syncthreads();

  { // ---- phase C: wave w owns l in [w*64, w*64+64); V cols from LDS ----
    s8v pa = *(const s8v*)&P_lds[l16 * 32 + ((kg * 8) ^ ((l16 & 3) << 3))];
    f4v oa[4];
    #pragma unroll
    for (int nt = 0; nt < 4; ++nt) oa[nt] = {0.f, 0.f, 0.f, 0.f};
    #pragma unroll
    for (int nt = 0; nt < 4; ++nt) {
      int l = w * 64 + nt * 16 + l16;
      unsigned gcol = (unsigned)(l >> 3);
      int e2 = l & 7;
      s8v bv;
      #pragma unroll
      for (int i = 0; i < 8; ++i) {
        int r = kg * 8 + i;
        unsigned gc = (unsigned)((r & 7) ^ (((r >> 3) & 1) << 2));
        bv[i] = *(const short*)((const char*)V16 + r * 1024 +
                                ((gcol ^ gc) << 4) + e2 * 2);
      }
      oa[nt] = __builtin_amdgcn_mfma_f32_16x16x32_bf16(pa, bv, oa[nt], 0, 0, 0);
    }
    size_t base = (size_t)(b * NCH + chunk) * H_;
    #pragma unroll
    for (int nt = 0; nt < 4; ++nt) {
      int l = w * 64 + nt * 16 + l16;
      #pragma unroll
      for (int r = 0; r < 4; ++r) {
        int h = kg * 4 + r;
        acc_part[(base + h) * LOW_ + l] = (unsigned short)f2bf_s(oa[nt][r]);
      }
    }
  }
}

// Fused combine + project; 128 chunks (cross-wave reduce). grid (16,8,8) x 128.
__global__ __launch_bounds__(128) void reduce_proj_kernel(
    const float* __restrict__ m_part, const float* __restrict__ l_part,
    const unsigned short* __restrict__ acc_part, const float* __restrict__ FU,
    float* __restrict__ o_heads)
{
  int h = blockIdx.x, b = blockIdx.y, lz = blockIdx.z, t = threadIdx.x;
  int w = t >> 6, lane = t & 63;
  __shared__ float wls[NCH];
  __shared__ float red[4];
  __shared__ float pa0[128], pa1[128];
  __shared__ float wl_sh[64];
  float mc = m_part[(b * NCH + t) * H_ + h];
  float M = mc;
  #pragma unroll
  for (int d = 1; d < 64; d <<= 1) M = fmaxf(M, __shfl_xor(M, d));
  if (lane == 0) red[w] = M;
  __syncthreads();
  M = fmaxf(red[0], red[1]);
  float wc = expf(mc - M);
  wls[t] = wc;
  float L = l_part[(b * NCH + t) * H_ + h] * wc;
  #pragma unroll
  for (int d = 1; d < 64; d <<= 1) L += __shfl_xor(L, d);
  if (lane == 0) red[2 + w] = L;
  __syncthreads();
  float Linv = 1.0f / (red[2] + red[3]);
  {
    int p = t & 31, ch = t >> 5;
    int l0 = lz * 64 + p * 2;
    float a0 = 0.f, a1 = 0.f;
    const unsigned short* ap =
        acc_part + ((size_t)(b * NCH + ch * 32) * H_ + h) * LOW_ + l0;
    #pragma unroll 4
    for (int c = 0; c < 32; ++c) {
      unsigned pk = *(const unsigned*)(ap + (size_t)c * H_ * LOW_);
      float wc2 = wls[ch * 32 + c];
      a0 = fmaf(bf2f((unsigned short)(pk & 0xffffu)), wc2, a0);
      a1 = fmaf(bf2f((unsigned short)(pk >> 16)),     wc2, a1);
    }
    pa0[t] = a0; pa1[t] = a1;
  }
  __syncthreads();
  if (t < 32) {
    float s0 = pa0[t] + pa0[t + 32] + pa0[t + 64] + pa0[t + 96];
    float s1 = pa1[t] + pa1[t + 32] + pa1[t + 64] + pa1[t + 96];
    wl_sh[t * 2]     = s0 * Linv;
    wl_sh[t * 2 + 1] = s1 * Linv;
  }
  __syncthreads();
  {
    float a = 0.f;
    const float* fp = FU + (size_t)(lz * 64) * (2 * E_) + E_ + h * HD_ + t;
    #pragma unroll 4
    for (int l = 0; l < 64; ++l)
      a = fmaf(wl_sh[l], fp[(size_t)l * (2 * E_)], a);
    atomicAdd(&o_heads[(b * H_ + h) * HD_ + t], a);
  }
}

extern "C" void kernel_launch(void* const* d_in, const int* in_sizes, int n_in,
                              void* d_out, int out_size, void* d_ws, size_t ws_size,
                              hipStream_t stream)
{
  const float* x    = (const float*)d_in[0];
  const float* ckvc = (const float*)d_in[1];
  const float* krc  = (const float*)d_in[2];
  const float* Wdq  = (const float*)d_in[3];
  const float* Wuq  = (const float*)d_in[4];
  const float* Wqr  = (const float*)d_in[5];
  const float* Wdkv = (const float*)d_in[6];
  const float* Wkr  = (const float*)d_in[7];
  const float* FU   = (const float*)d_in[8];
  const float* Wo   = (const float*)d_in[9];
  float* out = (float*)d_out;

  char* ws = (char*)d_ws;
  // zeroed prefix (55296 floats):
  float* Cq             = (float*)(ws + 0);        // 65536 B
  float* Qc             = (float*)(ws + 65536);    // 65536 B
  float* qr_pre         = (float*)(ws + 131072);   // 4096 B
  float* ckvn           = (float*)(ws + 135168);   // 16384 B
  float* krn            = (float*)(ws + 151552);   // 4096 B
  float* o_heads        = (float*)(ws + 155648);   // 65536 B  [prefix end 221184]
  unsigned short* qeff  = (unsigned short*)(ws + 221184);  // 131072 B
  float* m_part         = (float*)(ws + 352256);   // 65536 B
  float* l_part         = (float*)(ws + 417792);   // 65536 B
  unsigned short* accp  = (unsigned short*)(ws + 483328);  // 16777216 B (~17.3 MB)

  // Zero all atomic targets
  init_kernel<<<280, 256, 0, stream>>>((float*)ws, out);

  // Cq = x@Wdq ; ckv_new = x@Wdkv ; kr_new = x@Wkr
  matvec8<<<dim3(21, 64), 128, 0, stream>>>(x, E_, Wdq, E_, Cq,
                                            Wdkv, LOW_, ckvn, Wkr, HD_, krn);
  // Qc = Cq@Wuq ; qr_pre = Cq@Wqr
  matvec8<<<dim3(17, 64), 128, 0, stream>>>(Cq, E_, Wuq, E_, Qc,
                                            Wqr, HD_, qr_pre,
                                            (const float*)nullptr, 0, (float*)nullptr);
  qeff_kernel<<<dim3(64, 8), 256, 0, stream>>>(Qc, FU, qeff);
  attn_kernel<<<dim3(128, 8), 512, 0, stream>>>(ckvc, ckvn, qeff, krc, krn,
                                                qr_pre, accp, m_part, l_part);
  reduce_proj_kernel<<<dim3(16, 8, 8), 128, 0, stream>>>(m_part, l_part, accp,
                                                         FU, o_heads);
  // out = o_heads @ Wo
  matvec8<<<dim3(16, 64), 128, 0, stream>>>(o_heads, E_, Wo, E_, out,
                                            (const float*)nullptr, 0, (float*)nullptr,
                                            (const float*)nullptr, 0, (float*)nullptr);
}